// Round 12
// baseline (79.297 us; speedup 1.0000x reference)
//
#include <hip/hip_runtime.h>

// B=64, T=128, N=128, M=512, 4M=2048, BT=8192
typedef __attribute__((ext_vector_type(8))) short bfrag;   // 8 bf16 = 4 VGPR
typedef __attribute__((ext_vector_type(4))) float f32x4;

// 2*log2(e): tanh(x) = 1 - 2/(2^(C_SCALE*x)+1)
#define C_SCALE 2.885390081777926815f

__device__ __forceinline__ float fast_rcp(float x){
#if __has_builtin(__builtin_amdgcn_rcpf)
  return __builtin_amdgcn_rcpf(x);
#else
  return 1.0f/x;
#endif
}
__device__ __forceinline__ float fexp2(float x){
#if __has_builtin(__builtin_amdgcn_exp2f)
  return __builtin_amdgcn_exp2f(x);
#else
  return exp2f(x);
#endif
}
__device__ __forceinline__ float sigm(float x){ return fast_rcp(1.0f + __expf(-x)); }
__device__ __forceinline__ float tanh_f(float x){ return 1.0f - 2.0f*fast_rcp(__expf(2.0f*x) + 1.0f); }
__device__ __forceinline__ unsigned short f2bf(float f){
  unsigned u = __float_as_uint(f);
  return (unsigned short)((u + 0x7fffu + ((u>>16)&1u)) >> 16);
}
// async global->LDS, 16B per lane; LDS dest must be wave-uniform base + lane*16
__device__ __forceinline__ void gload16(const void* g, void* l){
  __builtin_amdgcn_global_load_lds((const __attribute__((address_space(1))) void*)g,
                                   (__attribute__((address_space(3))) void*)l, 16, 0, 0);
}

// ---------------------------------------------------------------------------
// PREP: fused { xconv(512) | Wl transp(64) | We transp+perm(32) | k4->eU(128) | k1(256) }
// grid 992, block 256.  k4 writes eU in k-tiled layout: UTb[b][k8(16)][n(128)][8]
__global__ __launch_bounds__(256) void prep(const float* __restrict__ X,
                                            unsigned short* __restrict__ Xbf,
                                            const float* __restrict__ Wl,
                                            unsigned short* __restrict__ Wlt,
                                            const float* __restrict__ We,
                                            unsigned short* __restrict__ Wet,
                                            const float* __restrict__ h0,
                                            const float* __restrict__ Ul,
                                            float* __restrict__ Uhp,
                                            const float* __restrict__ Ue,
                                            const float* __restrict__ bUe,
                                            unsigned short* __restrict__ UTb){
  __shared__ __align__(16) float sh[6600];   // 26.4 KB, reused per branch
  const int tid = threadIdx.x;
  const int bid = blockIdx.x;

  if (bid < 512){                       // ---- xconv: X f32 -> bf16
    const int i = (bid*256 + tid)*8;
    float4 a = *(const float4*)&X[i];
    float4 b = *(const float4*)&X[i+4];
    ushort4 lo, hi;
    lo.x=f2bf(a.x); lo.y=f2bf(a.y); lo.z=f2bf(a.z); lo.w=f2bf(a.w);
    hi.x=f2bf(b.x); hi.y=f2bf(b.y); hi.z=f2bf(b.z); hi.w=f2bf(b.w);
    *(ushort4*)&Xbf[i] = lo; *(ushort4*)&Xbf[i+4] = hi;
  } else if (bid < 608){                // ---- transpose f32 [K][N] -> bf16 [N][K]
    // For We: output k' is h/c-interleaved (k'=2m -> src m, k'=2m+1 -> src 512+m)
    const float* in; unsigned short* outp; int K, N, j0, k0, perm;
    if (bid < 576){ int r = bid-512; in = Wl; outp = Wlt; K = 128;  N = 2048; j0 = (r&31)*64; k0 = (r>>5)*64; perm = 0; }
    else          { int r = bid-576; in = We; outp = Wet; K = 1024; N = 128;  j0 = (r&1)*64;  k0 = (r>>1)*64; perm = 1; }
    float (*t)[68] = (float(*)[68])sh;
#pragma unroll
    for (int i=0;i<4;i++){
      int idx = tid + i*256;
      int r = idx>>4, c4 = idx&15;
      int kk = k0 + r;
      int srow = perm ? ((kk&1) ? 512 + (kk>>1) : (kk>>1)) : kk;
      *(float4*)&t[r][c4*4] = *(const float4*)&in[srow*N + j0 + c4*4];
    }
    __syncthreads();
#pragma unroll
    for (int i=0;i<4;i++){
      int idx = tid + i*256;
      int r = idx>>4, c4 = idx&15;
      ushort4 o;
      o.x = f2bf(t[c4*4+0][r]); o.y = f2bf(t[c4*4+1][r]);
      o.z = f2bf(t[c4*4+2][r]); o.w = f2bf(t[c4*4+3][r]);
      *(ushort4*)&outp[(j0+r)*K + k0 + c4*4] = o;
    }
  } else if (bid < 736){                // ---- k4: eU = 2^(C*(U+bUe)), k-tiled layout
    const int r = bid - 608;            // 0..127
    const int nh = r & 1, b = r >> 1;
    float (*Xs)[68]  = (float(*)[68])sh;            // 32x68
    float (*Us)[132] = (float(*)[132])(sh + 2176);  // 32x132
    const int tc5 = tid & 31, tr8 = tid >> 5;       // k-quad, n-group
    f32x4 a4[8];
#pragma unroll
    for (int j=0;j<8;j++) a4[j] = (f32x4){0.f,0.f,0.f,0.f};
    for (int tk=0; tk<4; tk++){
#pragma unroll
      for (int i=0;i<2;i++){
        int idx = tid + i*256;
        int t = idx>>4, nq = idx&15;
        *(float4*)&Xs[t][nq*4] = *(const float4*)&X[(b*128 + tk*32 + t)*128 + nh*64 + nq*4];
      }
#pragma unroll
      for (int i=0;i<4;i++){
        int idx = tid + i*256;
        int t = idx>>5, kq = idx&31;
        *(float4*)&Us[t][kq*4] = *(const float4*)&Ue[(tk*32+t)*128 + kq*4];
      }
      __syncthreads();
#pragma unroll 4
      for (int t=0;t<32;t++){
        f32x4 u4 = *(const f32x4*)&Us[t][tc5*4];
        f32x4 x0 = *(const f32x4*)&Xs[t][tr8*8];
        f32x4 x1 = *(const f32x4*)&Xs[t][tr8*8+4];
        a4[0] += x0.x*u4; a4[1] += x0.y*u4; a4[2] += x0.z*u4; a4[3] += x0.w*u4;
        a4[4] += x1.x*u4; a4[5] += x1.y*u4; a4[6] += x1.z*u4; a4[7] += x1.w*u4;
      }
      __syncthreads();
    }
    const f32x4 bu = *(const f32x4*)&bUe[tc5*4];
    const int ktile = tc5 >> 1, khalf = tc5 & 1;    // k = tc5*4.. -> tile=k/8, off=(k%8)
#pragma unroll
    for (int j=0;j<8;j++){
      const int n = nh*64 + tr8*8 + j;
      f32x4 v = a4[j] + bu;
      ushort4 o;
      o.x = f2bf(fexp2(C_SCALE*v.x)); o.y = f2bf(fexp2(C_SCALE*v.y));
      o.z = f2bf(fexp2(C_SCALE*v.z)); o.w = f2bf(fexp2(C_SCALE*v.w));
      *(ushort4*)&UTb[b*16384 + ktile*1024 + n*8 + khalf*4] = o;
    }
  } else {                              // ---- k1: Uhp[kc][b][j] partials
    const int r = bid - 736;
    const int jc = r & 15;
    const int bc = (r>>4) >> 2, kc = (r>>4) & 3;
    float (*h0s)[128] = (float(*)[128])sh;
#pragma unroll
    for (int i=0;i<2;i++){
      int idx = tid + i*256;
      int bi = idx>>5, kq = idx&31;
      *(float4*)&h0s[bi][kq*4] = *(const float4*)&h0[(bc*16+bi)*512 + kc*128 + kq*4];
    }
    __syncthreads();
    const int jj = tid & 127, bh = tid >> 7;
    const int j = jc*128 + jj;
    float acc[8];
#pragma unroll
    for (int i=0;i<8;i++) acc[i]=0.f;
    for (int k=0;k<128;k+=4){
      float w0 = Ul[(kc*128+k+0)*2048 + j];
      float w1 = Ul[(kc*128+k+1)*2048 + j];
      float w2 = Ul[(kc*128+k+2)*2048 + j];
      float w3 = Ul[(kc*128+k+3)*2048 + j];
#pragma unroll
      for (int bi=0;bi<8;bi++){
        float4 h4 = *(const float4*)&h0s[bh*8+bi][k];
        acc[bi] += h4.x*w0 + h4.y*w1 + h4.z*w2 + h4.w*w3;
      }
    }
#pragma unroll
    for (int bi=0;bi<8;bi++)
      Uhp[kc*131072 + (bc*16 + bh*8 + bi)*2048 + j] = acc[bi];
  }
}

// ---------------------------------------------------------------------------
// K2: z = X@Wl + Uh -> gates -> hc (h/c interleaved, packed uint stores)
// Split-K staging (2x32KB).  grid 1024 (mc&15, b>>4), block 256
__global__ __launch_bounds__(256) void k2_k(const unsigned short* __restrict__ Xbf,
                                            const unsigned short* __restrict__ Wlt,
                                            const float* __restrict__ Uhp,
                                            const float* __restrict__ bl,
                                            const float* __restrict__ s0,
                                            unsigned int* __restrict__ hci){
  __shared__ __align__(16) char lds[32768];
  const int tid = threadIdx.x;
  const int mc = blockIdx.x & 15, b = blockIdx.x >> 4;
  const int bt0 = b*128;
  const int lane = tid & 63, wave = tid >> 6;
  const int wr = wave >> 1, wc = wave & 1;

  f32x4 acc[4][4];                 // [mt][gate]
#pragma unroll
  for (int mt=0;mt<4;mt++)
#pragma unroll
    for (int nt=0;nt<4;nt++) acc[mt][nt] = (f32x4){0.f,0.f,0.f,0.f};

  for (int kh=0; kh<2; kh++){      // two 64-k halves, 32KB LDS each
#pragma unroll
    for (int i=0;i<4;i++){
      int g = tid + i*256;         // 1024 granules: 128 rows x 8
      int r = g>>3, G = g&7;
      gload16(Xbf + (bt0+r)*128 + kh*64 + ((G ^ (r&7))<<3), lds + g*16);
    }
#pragma unroll
    for (int i=0;i<4;i++){
      int g = tid + i*256;         // 1024 granules: 128 cols x 8
      int c = g>>3, G = g&7;
      int q = c>>4;
      int j = (q&3)*512 + mc*32 + ((q>>2)<<4) + (c&15);
      gload16(Wlt + j*128 + kh*64 + ((G ^ (c&7))<<3), lds + 16384 + g*16);
    }
    __syncthreads();
#pragma unroll
    for (int ks2=0; ks2<2; ks2++){
      const int kb = ks2*64 + ((lane>>4)<<4);
      bfrag a[4], bb[4];
#pragma unroll
      for (int mt=0;mt<4;mt++){
        int r = wr*64 + mt*16 + (lane&15);
        a[mt] = *(const bfrag*)&lds[r*128 + (kb ^ ((r&7)<<4))];
      }
#pragma unroll
      for (int nt=0;nt<4;nt++){
        int c = wc*64 + nt*16 + (lane&15);
        bb[nt] = *(const bfrag*)&lds[16384 + c*128 + (kb ^ ((c&7)<<4))];
      }
#pragma unroll
      for (int mt=0;mt<4;mt++)
#pragma unroll
        for (int nt=0;nt<4;nt++)
          acc[mt][nt] = __builtin_amdgcn_mfma_f32_16x16x32_bf16(a[mt], bb[nt], acc[mt][nt], 0, 0, 0);
    }
    __syncthreads();
  }

  const int mloc = mc*32 + wc*16 + (lane&15);     // 0..511
  float uh[4];
#pragma unroll
  for (int g=0;g<4;g++){
    int j = g*512 + mloc;
    uh[g] = bl[j] + Uhp[0*131072 + b*2048 + j] + Uhp[1*131072 + b*2048 + j]
                  + Uhp[2*131072 + b*2048 + j] + Uhp[3*131072 + b*2048 + j];
  }
  const float s0v = s0[b*512 + mloc];
#pragma unroll
  for (int mt=0;mt<4;mt++){
#pragma unroll
    for (int reg=0;reg<4;reg++){
      int row = wr*64 + mt*16 + (lane>>4)*4 + reg;
      float zi = acc[mt][0][reg] + uh[0];
      float zf = acc[mt][1][reg] + uh[1];
      float zc = acc[mt][2][reg] + uh[2];
      float zo = acc[mt][3][reg] + uh[3];
      float fi = sigm(zi), ff = sigm(zf), fo = sigm(zo);
      float cv = ff*s0v + fi*tanh_f(zc);
      float hv = fo*tanh_f(cv);
      // hc interleaved: k'=2m -> h, k'=2m+1 -> c  (Wet rows permuted to match)
      hci[(bt0+row)*512 + mloc] = (unsigned)f2bf(hv) | ((unsigned)f2bf(cv) << 16);
    }
  }
}

// ---------------------------------------------------------------------------
// K35: fused k3+k5 with corrected staging ratio (32 rows x FULL 128 cols).
//  Phase 1: eA[32][128] = 2^(C*(hc_rows @ Wet^T + bWe)) -> LDS (overlay)
//  Phase 2: s = 1/(1+eA*eU); score' = -2*sum v*s; softmax over n; out = X*alpha
//  Score runs in TWO passes of 8 t (sc[8] regs) to cap VGPR pressure.
// grid (4 tpc, 64 b), block 256 (4 waves 2x2 of 16rows x 64cols)
__global__ __launch_bounds__(256) void k35(const unsigned short* __restrict__ hc,
                                           const unsigned short* __restrict__ Wet,
                                           const float* __restrict__ bWe,
                                           const float* __restrict__ X,
                                           const unsigned short* __restrict__ UTb,
                                           const float* __restrict__ ve,
                                           float* __restrict__ out){
  __shared__ __align__(16) char lds[40960];     // ldsA 8KB | ldsB 32KB; eAs overlays after MFMA
  __shared__ __align__(16) float vs[128];
  __shared__ float redm[4][16], reds[4][16];
  const int tid = threadIdx.x;
  const int tpc = blockIdx.x;   // 0..3
  const int b   = blockIdx.y;   // 0..63
  const int bt0 = b*128 + tpc*32;
  const int lane = tid & 63, wave = tid >> 6;
  const int wr = wave >> 1, wc = wave & 1;

  if (tid < 128) vs[tid] = ve[tid];

  f32x4 acc[4];
#pragma unroll
  for (int nt=0;nt<4;nt++) acc[nt] = (f32x4){0.f,0.f,0.f,0.f};

  char* ldsA = lds;
  char* ldsB = lds + 8192;

  for (int ks=0; ks<8; ks++){
    const int k0 = ks*128;
#pragma unroll
    for (int i=0;i<2;i++){
      int g = tid + i*256;          // 512 granules: 32 rows x 16
      int r = g>>4, G = g&15;
      gload16(hc + (bt0+r)*1024 + k0 + ((G ^ (r&7))<<3), ldsA + g*16);
    }
#pragma unroll
    for (int i=0;i<8;i++){
      int g = tid + i*256;          // 2048 granules: 128 n x 16
      int nn = g>>4, G = g&15;
      gload16(Wet + nn*1024 + k0 + ((G ^ (nn&7))<<3), ldsB + g*16);
    }
    __syncthreads();
#pragma unroll
    for (int kk=0;kk<4;kk++){
      const int kb = kk*64 + ((lane>>4)<<4);
      const int r = wr*16 + (lane&15);
      bfrag a = *(const bfrag*)&ldsA[r*256 + (kb ^ ((r&7)<<4))];
#pragma unroll
      for (int nt=0;nt<4;nt++){
        const int c = wc*64 + nt*16 + (lane&15);
        bfrag bv = *(const bfrag*)&ldsB[c*256 + (kb ^ ((c&7)<<4))];
        acc[nt] = __builtin_amdgcn_mfma_f32_16x16x32_bf16(a, bv, acc[nt], 0, 0, 0);
      }
    }
    __syncthreads();
  }

  // eA -> LDS overlay (ldsA/ldsB dead after final barrier above)
  float (*eAs)[132] = (float(*)[132])lds;       // 32x132 f32 = 16.9KB
#pragma unroll
  for (int nt=0;nt<4;nt++){
    const int col = wc*64 + nt*16 + (lane&15);
    const float bw = bWe[col];
#pragma unroll
    for (int reg=0;reg<4;reg++){
      const int row = wr*16 + (lane>>4)*4 + reg;
      eAs[row][col] = fexp2(C_SCALE*(acc[nt][reg] + bw));
    }
  }
  __syncthreads();

  // ---- score phase: 32 t's, two passes of 8 sv-slots (16 slots x tpair)
  const int tpair = tid>>7, n = tid&127, wid = tid>>6;
  const unsigned short* urow = UTb + b*16384 + n*8;   // [b][k8][n][8]
  float sv[16];

#pragma unroll
  for (int half=0; half<2; half++){
    f32x4 sc[8];
#pragma unroll
    for (int tt=0;tt<8;tt++) sc[tt] = (f32x4){0.f,0.f,0.f,0.f};
#pragma unroll 2
    for (int k8=0; k8<16; k8++){
      uint4 u = *(const uint4*)(urow + k8*1024);
      f32x4 ua, ub;   // eU
      ua.x = __uint_as_float(u.x<<16); ua.y = __uint_as_float(u.x & 0xffff0000u);
      ua.z = __uint_as_float(u.y<<16); ua.w = __uint_as_float(u.y & 0xffff0000u);
      ub.x = __uint_as_float(u.z<<16); ub.y = __uint_as_float(u.z & 0xffff0000u);
      ub.z = __uint_as_float(u.w<<16); ub.w = __uint_as_float(u.w & 0xffff0000u);
      const f32x4 va = *(const f32x4*)&vs[k8*8];
      const f32x4 vb = *(const f32x4*)&vs[k8*8+4];
#pragma unroll
      for (int tt=0; tt<8; tt++){
        const float* Ar = &eAs[(half*8+tt)*2+tpair][k8*8];
        f32x4 ea = *(const f32x4*)Ar;
        f32x4 eb = *(const f32x4*)(Ar+4);
        f32x4 ra, rb;   // 1/(1 + eA*eU): 1 fma + 1 rcp per elem
        ra.x = fast_rcp(ea.x*ua.x + 1.f); ra.y = fast_rcp(ea.y*ua.y + 1.f);
        ra.z = fast_rcp(ea.z*ua.z + 1.f); ra.w = fast_rcp(ea.w*ua.w + 1.f);
        rb.x = fast_rcp(eb.x*ub.x + 1.f); rb.y = fast_rcp(eb.y*ub.y + 1.f);
        rb.z = fast_rcp(eb.z*ub.z + 1.f); rb.w = fast_rcp(eb.w*ub.w + 1.f);
        sc[tt] += va*ra;
        sc[tt] += vb*rb;
      }
    }
#pragma unroll
    for (int tt=0;tt<8;tt++)
      sv[half*8+tt] = -2.f*((sc[tt].x + sc[tt].y) + (sc[tt].z + sc[tt].w));
  }

  // batched softmax over n=128 (2 waves per t), 16 slots
#pragma unroll
  for (int st=0;st<16;st++){
    float m = sv[st];
#pragma unroll
    for (int off=32; off>0; off>>=1) m = fmaxf(m, __shfl_xor(m, off));
    if ((tid&63)==0) redm[wid][st] = m;
  }
  __syncthreads();
  float evv[16];
#pragma unroll
  for (int st=0;st<16;st++){
    const float M = fmaxf(redm[tpair*2][st], redm[tpair*2+1][st]);
    float e = __expf(sv[st] - M);
    evv[st] = e;
    float s = e;
#pragma unroll
    for (int off=32; off>0; off>>=1) s += __shfl_xor(s, off);
    if ((tid&63)==0) reds[wid][st] = s;
  }
  __syncthreads();
#pragma unroll
  for (int st=0;st<16;st++){
    const float S = reds[tpair*2][st] + reds[tpair*2+1][st];
    const float alpha = evv[st] * fast_rcp(S);
    const int g = (bt0 + st*2 + tpair)*128 + n;
    out[g] = X[g] * alpha;
  }
}

// ---------------------------------------------------------------------------
extern "C" void kernel_launch(void* const* d_in, const int* in_sizes, int n_in,
                              void* d_out, int out_size, void* d_ws, size_t ws_size,
                              hipStream_t stream){
  (void)in_sizes; (void)n_in; (void)out_size; (void)ws_size;
  const float* X   = (const float*)d_in[0];
  const float* h0  = (const float*)d_in[1];
  const float* s0  = (const float*)d_in[2];
  const float* Wl  = (const float*)d_in[3];
  const float* Ul  = (const float*)d_in[4];
  const float* bl  = (const float*)d_in[5];
  const float* We  = (const float*)d_in[6];
  const float* bWe = (const float*)d_in[7];
  const float* Ue  = (const float*)d_in[8];
  const float* bUe = (const float*)d_in[9];
  const float* ve  = (const float*)d_in[10];
  // d_in[11] (b_ve) is softmax-shift-invariant: skipped.
  float* out = (float*)d_out;

  char* ws = (char*)d_ws;
  unsigned short* Wlt = (unsigned short*)(ws + 0);          // 2048x128 bf16 (512 KB)
  unsigned short* Wet = (unsigned short*)(ws + 524288);     // 128x1024 bf16 (256 KB, k-permuted)
  unsigned short* Xbf = (unsigned short*)(ws + 786432);     // 8192x128 bf16 (2 MB)
  unsigned short* UTb = (unsigned short*)(ws + 2883584);    // 64x16x128x8 bf16 (2 MB, eU k-tiled)
  unsigned short* hc  = (unsigned short*)(ws + 4980736);    // 8192x1024 bf16 (16 MB, h/c interleaved)
  float*          Uhp = (float*)(ws + 21757952);            // 4x64x2048 f32 (2 MB)
  unsigned int*   hci = (unsigned int*)hc;

  prep <<<dim3(992),   256, 0, stream>>>(X, Xbf, Wl, Wlt, We, Wet, h0, Ul, Uhp, Ue, bUe, UTb);
  k2_k <<<dim3(1024),  256, 0, stream>>>(Xbf, Wlt, Uhp, bl, s0, hci);
  k35  <<<dim3(4,64),  256, 0, stream>>>(hc, Wet, bWe, X, UTb, ve, out);
}

// Round 13
// 61.863 us; speedup vs baseline: 1.2818x; 1.2818x over previous
//
#include <hip/hip_runtime.h>

// B=64, T=128, N=128, M=512, 4M=2048, BT=8192
typedef __attribute__((ext_vector_type(8))) short bfrag;   // 8 bf16 = 4 VGPR
typedef __attribute__((ext_vector_type(4))) float f32x4;

// 2*log2(e): tanh(x) = 1 - 2/(2^(C_SCALE*x)+1)
#define C_SCALE 2.885390081777926815f

__device__ __forceinline__ float fast_rcp(float x){
#if __has_builtin(__builtin_amdgcn_rcpf)
  return __builtin_amdgcn_rcpf(x);
#else
  return 1.0f/x;
#endif
}
__device__ __forceinline__ float fexp2(float x){
#if __has_builtin(__builtin_amdgcn_exp2f)
  return __builtin_amdgcn_exp2f(x);
#else
  return exp2f(x);
#endif
}
__device__ __forceinline__ float sigm(float x){ return fast_rcp(1.0f + __expf(-x)); }
__device__ __forceinline__ float tanh_f(float x){ return 1.0f - 2.0f*fast_rcp(__expf(2.0f*x) + 1.0f); }
__device__ __forceinline__ unsigned short f2bf(float f){
  unsigned u = __float_as_uint(f);
  return (unsigned short)((u + 0x7fffu + ((u>>16)&1u)) >> 16);
}
// async global->LDS, 16B per lane; LDS dest must be wave-uniform base + lane*16
__device__ __forceinline__ void gload16(const void* g, void* l){
  __builtin_amdgcn_global_load_lds((const __attribute__((address_space(1))) void*)g,
                                   (__attribute__((address_space(3))) void*)l, 16, 0, 0);
}

// ---------------------------------------------------------------------------
// PREP: fused { xconv(512) | Wl transp(64) | We transp+perm(32) | k4->eU(128) | k1(256) }
// grid 992, block 256.  k4 writes eU in k-tiled layout: UTb[b][k8(16)][n(128)][8]
__global__ __launch_bounds__(256) void prep(const float* __restrict__ X,
                                            unsigned short* __restrict__ Xbf,
                                            const float* __restrict__ Wl,
                                            unsigned short* __restrict__ Wlt,
                                            const float* __restrict__ We,
                                            unsigned short* __restrict__ Wet,
                                            const float* __restrict__ h0,
                                            const float* __restrict__ Ul,
                                            float* __restrict__ Uhp,
                                            const float* __restrict__ Ue,
                                            const float* __restrict__ bUe,
                                            unsigned short* __restrict__ UTb){
  __shared__ __align__(16) float sh[6600];   // 26.4 KB, reused per branch
  const int tid = threadIdx.x;
  const int bid = blockIdx.x;

  if (bid < 512){                       // ---- xconv: X f32 -> bf16
    const int i = (bid*256 + tid)*8;
    float4 a = *(const float4*)&X[i];
    float4 b = *(const float4*)&X[i+4];
    ushort4 lo, hi;
    lo.x=f2bf(a.x); lo.y=f2bf(a.y); lo.z=f2bf(a.z); lo.w=f2bf(a.w);
    hi.x=f2bf(b.x); hi.y=f2bf(b.y); hi.z=f2bf(b.z); hi.w=f2bf(b.w);
    *(ushort4*)&Xbf[i] = lo; *(ushort4*)&Xbf[i+4] = hi;
  } else if (bid < 608){                // ---- transpose f32 [K][N] -> bf16 [N][K]
    // For We: output k' is h/c-interleaved (k'=2m -> src m, k'=2m+1 -> src 512+m)
    const float* in; unsigned short* outp; int K, N, j0, k0, perm;
    if (bid < 576){ int r = bid-512; in = Wl; outp = Wlt; K = 128;  N = 2048; j0 = (r&31)*64; k0 = (r>>5)*64; perm = 0; }
    else          { int r = bid-576; in = We; outp = Wet; K = 1024; N = 128;  j0 = (r&1)*64;  k0 = (r>>1)*64; perm = 1; }
    float (*t)[68] = (float(*)[68])sh;
#pragma unroll
    for (int i=0;i<4;i++){
      int idx = tid + i*256;
      int r = idx>>4, c4 = idx&15;
      int kk = k0 + r;
      int srow = perm ? ((kk&1) ? 512 + (kk>>1) : (kk>>1)) : kk;
      *(float4*)&t[r][c4*4] = *(const float4*)&in[srow*N + j0 + c4*4];
    }
    __syncthreads();
#pragma unroll
    for (int i=0;i<4;i++){
      int idx = tid + i*256;
      int r = idx>>4, c4 = idx&15;
      ushort4 o;
      o.x = f2bf(t[c4*4+0][r]); o.y = f2bf(t[c4*4+1][r]);
      o.z = f2bf(t[c4*4+2][r]); o.w = f2bf(t[c4*4+3][r]);
      *(ushort4*)&outp[(j0+r)*K + k0 + c4*4] = o;
    }
  } else if (bid < 736){                // ---- k4: eU = 2^(C*(U+bUe)), k-tiled layout
    const int r = bid - 608;            // 0..127
    const int nh = r & 1, b = r >> 1;
    float (*Xs)[68]  = (float(*)[68])sh;            // 32x68
    float (*Us)[132] = (float(*)[132])(sh + 2176);  // 32x132
    const int tc5 = tid & 31, tr8 = tid >> 5;       // k-quad, n-group
    f32x4 a4[8];
#pragma unroll
    for (int j=0;j<8;j++) a4[j] = (f32x4){0.f,0.f,0.f,0.f};
    for (int tk=0; tk<4; tk++){
#pragma unroll
      for (int i=0;i<2;i++){
        int idx = tid + i*256;
        int t = idx>>4, nq = idx&15;
        *(float4*)&Xs[t][nq*4] = *(const float4*)&X[(b*128 + tk*32 + t)*128 + nh*64 + nq*4];
      }
#pragma unroll
      for (int i=0;i<4;i++){
        int idx = tid + i*256;
        int t = idx>>5, kq = idx&31;
        *(float4*)&Us[t][kq*4] = *(const float4*)&Ue[(tk*32+t)*128 + kq*4];
      }
      __syncthreads();
#pragma unroll 4
      for (int t=0;t<32;t++){
        f32x4 u4 = *(const f32x4*)&Us[t][tc5*4];
        f32x4 x0 = *(const f32x4*)&Xs[t][tr8*8];
        f32x4 x1 = *(const f32x4*)&Xs[t][tr8*8+4];
        a4[0] += x0.x*u4; a4[1] += x0.y*u4; a4[2] += x0.z*u4; a4[3] += x0.w*u4;
        a4[4] += x1.x*u4; a4[5] += x1.y*u4; a4[6] += x1.z*u4; a4[7] += x1.w*u4;
      }
      __syncthreads();
    }
    const f32x4 bu = *(const f32x4*)&bUe[tc5*4];
    const int ktile = tc5 >> 1, khalf = tc5 & 1;    // k = tc5*4.. -> tile=k/8, off=(k%8)
#pragma unroll
    for (int j=0;j<8;j++){
      const int n = nh*64 + tr8*8 + j;
      f32x4 v = a4[j] + bu;
      ushort4 o;
      o.x = f2bf(fexp2(C_SCALE*v.x)); o.y = f2bf(fexp2(C_SCALE*v.y));
      o.z = f2bf(fexp2(C_SCALE*v.z)); o.w = f2bf(fexp2(C_SCALE*v.w));
      *(ushort4*)&UTb[b*16384 + ktile*1024 + n*8 + khalf*4] = o;
    }
  } else {                              // ---- k1: Uhp[kc][b][j] partials
    const int r = bid - 736;
    const int jc = r & 15;
    const int bc = (r>>4) >> 2, kc = (r>>4) & 3;
    float (*h0s)[128] = (float(*)[128])sh;
#pragma unroll
    for (int i=0;i<2;i++){
      int idx = tid + i*256;
      int bi = idx>>5, kq = idx&31;
      *(float4*)&h0s[bi][kq*4] = *(const float4*)&h0[(bc*16+bi)*512 + kc*128 + kq*4];
    }
    __syncthreads();
    const int jj = tid & 127, bh = tid >> 7;
    const int j = jc*128 + jj;
    float acc[8];
#pragma unroll
    for (int i=0;i<8;i++) acc[i]=0.f;
    for (int k=0;k<128;k+=4){
      float w0 = Ul[(kc*128+k+0)*2048 + j];
      float w1 = Ul[(kc*128+k+1)*2048 + j];
      float w2 = Ul[(kc*128+k+2)*2048 + j];
      float w3 = Ul[(kc*128+k+3)*2048 + j];
#pragma unroll
      for (int bi=0;bi<8;bi++){
        float4 h4 = *(const float4*)&h0s[bh*8+bi][k];
        acc[bi] += h4.x*w0 + h4.y*w1 + h4.z*w2 + h4.w*w3;
      }
    }
#pragma unroll
    for (int bi=0;bi<8;bi++)
      Uhp[kc*131072 + (bc*16 + bh*8 + bi)*2048 + j] = acc[bi];
  }
}

// ---------------------------------------------------------------------------
// K2: z = X@Wl + Uh -> gates -> hc (h/c interleaved, packed uint stores)
// Split-K staging (2x32KB).  grid 1024 (mc&15, b>>4), block 256
__global__ __launch_bounds__(256) void k2_k(const unsigned short* __restrict__ Xbf,
                                            const unsigned short* __restrict__ Wlt,
                                            const float* __restrict__ Uhp,
                                            const float* __restrict__ bl,
                                            const float* __restrict__ s0,
                                            unsigned int* __restrict__ hci){
  __shared__ __align__(16) char lds[32768];
  const int tid = threadIdx.x;
  const int mc = blockIdx.x & 15, b = blockIdx.x >> 4;
  const int bt0 = b*128;
  const int lane = tid & 63, wave = tid >> 6;
  const int wr = wave >> 1, wc = wave & 1;

  f32x4 acc[4][4];                 // [mt][gate]
#pragma unroll
  for (int mt=0;mt<4;mt++)
#pragma unroll
    for (int nt=0;nt<4;nt++) acc[mt][nt] = (f32x4){0.f,0.f,0.f,0.f};

  for (int kh=0; kh<2; kh++){      // two 64-k halves, 32KB LDS each
#pragma unroll
    for (int i=0;i<4;i++){
      int g = tid + i*256;         // 1024 granules: 128 rows x 8
      int r = g>>3, G = g&7;
      gload16(Xbf + (bt0+r)*128 + kh*64 + ((G ^ (r&7))<<3), lds + g*16);
    }
#pragma unroll
    for (int i=0;i<4;i++){
      int g = tid + i*256;         // 1024 granules: 128 cols x 8
      int c = g>>3, G = g&7;
      int q = c>>4;
      int j = (q&3)*512 + mc*32 + ((q>>2)<<4) + (c&15);
      gload16(Wlt + j*128 + kh*64 + ((G ^ (c&7))<<3), lds + 16384 + g*16);
    }
    __syncthreads();
#pragma unroll
    for (int ks2=0; ks2<2; ks2++){
      const int kb = ks2*64 + ((lane>>4)<<4);
      bfrag a[4], bb[4];
#pragma unroll
      for (int mt=0;mt<4;mt++){
        int r = wr*64 + mt*16 + (lane&15);
        a[mt] = *(const bfrag*)&lds[r*128 + (kb ^ ((r&7)<<4))];
      }
#pragma unroll
      for (int nt=0;nt<4;nt++){
        int c = wc*64 + nt*16 + (lane&15);
        bb[nt] = *(const bfrag*)&lds[16384 + c*128 + (kb ^ ((c&7)<<4))];
      }
#pragma unroll
      for (int mt=0;mt<4;mt++)
#pragma unroll
        for (int nt=0;nt<4;nt++)
          acc[mt][nt] = __builtin_amdgcn_mfma_f32_16x16x32_bf16(a[mt], bb[nt], acc[mt][nt], 0, 0, 0);
    }
    __syncthreads();
  }

  const int mloc = mc*32 + wc*16 + (lane&15);     // 0..511
  float uh[4];
#pragma unroll
  for (int g=0;g<4;g++){
    int j = g*512 + mloc;
    uh[g] = bl[j] + Uhp[0*131072 + b*2048 + j] + Uhp[1*131072 + b*2048 + j]
                  + Uhp[2*131072 + b*2048 + j] + Uhp[3*131072 + b*2048 + j];
  }
  const float s0v = s0[b*512 + mloc];
#pragma unroll
  for (int mt=0;mt<4;mt++){
#pragma unroll
    for (int reg=0;reg<4;reg++){
      int row = wr*64 + mt*16 + (lane>>4)*4 + reg;
      float zi = acc[mt][0][reg] + uh[0];
      float zf = acc[mt][1][reg] + uh[1];
      float zc = acc[mt][2][reg] + uh[2];
      float zo = acc[mt][3][reg] + uh[3];
      float fi = sigm(zi), ff = sigm(zf), fo = sigm(zo);
      float cv = ff*s0v + fi*tanh_f(zc);
      float hv = fo*tanh_f(cv);
      // hc interleaved: k'=2m -> h, k'=2m+1 -> c  (Wet rows permuted to match)
      hci[(bt0+row)*512 + mloc] = (unsigned)f2bf(hv) | ((unsigned)f2bf(cv) << 16);
    }
  }
}

// ---------------------------------------------------------------------------
// K3: eA = 2^(C*(hc @ Wet^T + bWe))  (full K=1024).  Tile 32 rows x 64 cols.
// grid 512, block 256
__global__ __launch_bounds__(256) void k3_k(const unsigned short* __restrict__ hc,
                                            const unsigned short* __restrict__ Wet,
                                            const float* __restrict__ bWe,
                                            float* __restrict__ eA){
  __shared__ __align__(16) char lds[24576];
  const int nc = blockIdx.x & 1, rc = blockIdx.x >> 1;
  const int bt0 = rc*32;
  const int tid = threadIdx.x;
  const int lane = tid & 63, wave = tid >> 6;
  const int wr = wave >> 1, wc = wave & 1;

  f32x4 acc[2];
  acc[0] = (f32x4){0.f,0.f,0.f,0.f};
  acc[1] = (f32x4){0.f,0.f,0.f,0.f};

  for (int ks=0; ks<8; ks++){
    const int k0 = ks*128;
#pragma unroll
    for (int i=0;i<2;i++){
      int g = tid + i*256;           // 512 granules: 32 rows x 16
      int r = g>>4, G = g&15;
      gload16(hc + (bt0+r)*1024 + k0 + ((G ^ (r&7))<<3), lds + g*16);
    }
#pragma unroll
    for (int i=0;i<4;i++){
      int g = tid + i*256;           // 1024 granules: 64 n-rows x 16
      int r = g>>4, G = g&15;
      gload16(Wet + (nc*64 + r)*1024 + k0 + ((G ^ (r&7))<<3), lds + 8192 + g*16);
    }
    __syncthreads();
#pragma unroll
    for (int kk=0;kk<4;kk++){
      const int kb = kk*64 + ((lane>>4)<<4);
      int r = wr*16 + (lane&15);
      bfrag a = *(const bfrag*)&lds[r*256 + (kb ^ ((r&7)<<4))];
      bfrag bb0, bb1;
      {
        int nn = wc*32 + 0*16 + (lane&15);
        bb0 = *(const bfrag*)&lds[8192 + nn*256 + (kb ^ ((nn&7)<<4))];
        nn = wc*32 + 1*16 + (lane&15);
        bb1 = *(const bfrag*)&lds[8192 + nn*256 + (kb ^ ((nn&7)<<4))];
      }
      acc[0] = __builtin_amdgcn_mfma_f32_16x16x32_bf16(a, bb0, acc[0], 0, 0, 0);
      acc[1] = __builtin_amdgcn_mfma_f32_16x16x32_bf16(a, bb1, acc[1], 0, 0, 0);
    }
    __syncthreads();
  }
#pragma unroll
  for (int reg=0; reg<4; reg++){
    int row = bt0 + wr*16 + (lane>>4)*4 + reg;
#pragma unroll
    for (int nt=0;nt<2;nt++){
      int col = nc*64 + wc*32 + nt*16 + (lane&15);
      eA[row*128 + col] = fexp2(C_SCALE*(acc[nt][reg] + bWe[col]));
    }
  }
}

// ---------------------------------------------------------------------------
// K5: s = 1/(1 + eA[t,k]*eU[n,k]);  score'[t,n] = -2*sum_k v[k]*s
// eU read DIRECTLY from global per-thread (k-tiled layout, coalesced uint4).
// LDS only As(4KB)+vs+red -> high occupancy.  grid (16 tch of 8 t, 64 b), block 256.
__global__ __launch_bounds__(256) void k5_k(const float* __restrict__ X,
                                            const unsigned short* __restrict__ UTb,
                                            const float* __restrict__ eA,
                                            const float* __restrict__ ve,
                                            float* __restrict__ out){
  __shared__ __align__(16) float As[8*128];             // 4KB (eA f32)
  __shared__ __align__(16) float vs[128];
  __shared__ float redm[4][4], reds[4][4];
  const int tid = threadIdx.x;
  const int tch = blockIdx.x;     // 0..15
  const int b   = blockIdx.y;     // 0..63
  const int tpair = tid>>7, n = tid&127, wid = tid>>6;

  {
    const float* asrc = eA + (b*128 + tch*8)*128;   // 1024 floats = 256 granules
    gload16(asrc + tid*4, (char*)As + tid*16);
    if (tid < 128) vs[tid] = ve[tid];
  }
  __syncthreads();

  f32x4 sc[4];
#pragma unroll
  for (int tt=0;tt<4;tt++) sc[tt] = (f32x4){0.f,0.f,0.f,0.f};

  const unsigned short* urow = UTb + b*16384 + n*8;   // [b][k8][n][8]
#pragma unroll 4
  for (int k8=0; k8<16; k8++){
    uint4 u = *(const uint4*)(urow + k8*1024);
    f32x4 ua, ub;   // eU
    ua.x = __uint_as_float(u.x<<16); ua.y = __uint_as_float(u.x & 0xffff0000u);
    ua.z = __uint_as_float(u.y<<16); ua.w = __uint_as_float(u.y & 0xffff0000u);
    ub.x = __uint_as_float(u.z<<16); ub.y = __uint_as_float(u.z & 0xffff0000u);
    ub.z = __uint_as_float(u.w<<16); ub.w = __uint_as_float(u.w & 0xffff0000u);
    const f32x4 va = *(const f32x4*)&vs[k8*8];
    const f32x4 vb = *(const f32x4*)&vs[k8*8+4];
#pragma unroll
    for (int tt=0; tt<4; tt++){
      const float* Ar = &As[(tt*2+tpair)*128 + k8*8];
      f32x4 ea = *(const f32x4*)Ar;
      f32x4 eb = *(const f32x4*)(Ar+4);
      f32x4 ra, rb;   // 1/(1 + eA*eU): 1 fma + 1 rcp per elem
      ra.x = fast_rcp(ea.x*ua.x + 1.f); ra.y = fast_rcp(ea.y*ua.y + 1.f);
      ra.z = fast_rcp(ea.z*ua.z + 1.f); ra.w = fast_rcp(ea.w*ua.w + 1.f);
      rb.x = fast_rcp(eb.x*ub.x + 1.f); rb.y = fast_rcp(eb.y*ub.y + 1.f);
      rb.z = fast_rcp(eb.z*ub.z + 1.f); rb.w = fast_rcp(eb.w*ub.w + 1.f);
      sc[tt] += va*ra;
      sc[tt] += vb*rb;
    }
  }

  // batched softmax over n=128 (2 waves per t)
  float sv[4];
#pragma unroll
  for (int tt=0;tt<4;tt++){
    float s = -2.f*((sc[tt].x + sc[tt].y) + (sc[tt].z + sc[tt].w));
    sv[tt] = s;
    float m = s;
#pragma unroll
    for (int off=32; off>0; off>>=1) m = fmaxf(m, __shfl_xor(m, off));
    if ((tid&63)==0) redm[wid][tt] = m;
  }
  __syncthreads();
  float evv[4];
#pragma unroll
  for (int tt=0;tt<4;tt++){
    const float M = fmaxf(redm[tpair*2][tt], redm[tpair*2+1][tt]);
    float e = __expf(sv[tt] - M);
    evv[tt] = e;
    float s = e;
#pragma unroll
    for (int off=32; off>0; off>>=1) s += __shfl_xor(s, off);
    if ((tid&63)==0) reds[wid][tt] = s;
  }
  __syncthreads();
#pragma unroll
  for (int tt=0;tt<4;tt++){
    const float S = reds[tpair*2][tt] + reds[tpair*2+1][tt];
    const float alpha = evv[tt] * fast_rcp(S);
    const int t = tch*8 + tt*2 + tpair;
    const int g = (b*128 + t)*128 + n;
    out[g] = X[g] * alpha;
  }
}

// ---------------------------------------------------------------------------
extern "C" void kernel_launch(void* const* d_in, const int* in_sizes, int n_in,
                              void* d_out, int out_size, void* d_ws, size_t ws_size,
                              hipStream_t stream){
  (void)in_sizes; (void)n_in; (void)out_size; (void)ws_size;
  const float* X   = (const float*)d_in[0];
  const float* h0  = (const float*)d_in[1];
  const float* s0  = (const float*)d_in[2];
  const float* Wl  = (const float*)d_in[3];
  const float* Ul  = (const float*)d_in[4];
  const float* bl  = (const float*)d_in[5];
  const float* We  = (const float*)d_in[6];
  const float* bWe = (const float*)d_in[7];
  const float* Ue  = (const float*)d_in[8];
  const float* bUe = (const float*)d_in[9];
  const float* ve  = (const float*)d_in[10];
  // d_in[11] (b_ve) is softmax-shift-invariant: skipped.
  float* out = (float*)d_out;

  char* ws = (char*)d_ws;
  unsigned short* Wlt = (unsigned short*)(ws + 0);          // 2048x128 bf16 (512 KB)
  unsigned short* Wet = (unsigned short*)(ws + 524288);     // 128x1024 bf16 (256 KB, k-permuted)
  unsigned short* Xbf = (unsigned short*)(ws + 786432);     // 8192x128 bf16 (2 MB)
  unsigned short* UTb = (unsigned short*)(ws + 2883584);    // 64x16x128x8 bf16 (2 MB, eU k-tiled)
  unsigned short* hc  = (unsigned short*)(ws + 4980736);    // 8192x1024 bf16 (16 MB, h/c interleaved)
  float*          Uhp = (float*)(ws + 21757952);            // 4x64x2048 f32 (2 MB)
  float*          eA  = (float*)(ws + 23855104);            // 8192x128 f32 (4 MB)
  unsigned int*   hci = (unsigned int*)hc;

  prep <<<dim3(992),    256, 0, stream>>>(X, Xbf, Wl, Wlt, We, Wet, h0, Ul, Uhp, Ue, bUe, UTb);
  k2_k <<<dim3(1024),   256, 0, stream>>>(Xbf, Wlt, Uhp, bl, s0, hci);
  k3_k <<<dim3(512),    256, 0, stream>>>(hc, Wet, bWe, eA);
  k5_k <<<dim3(16,64),  256, 0, stream>>>(X, UTb, eA, ve, out);
}